// Round 5
// baseline (954.857 us; speedup 1.0000x reference)
//
#include <hip/hip_runtime.h>
#include <math.h>

#define TPB 256
#define TPH 512

// problem sizes
constexpr int BSZ = 256, TL = 3, NV = 90, SV = 65, CH = 45;
constexpr int NS = NV*SV;            // 5850
constexpr int NP = TL*BSZ;           // 768 (t,b) pairs, q = t*256+b
constexpr int NM = NV*NV;            // 8100
constexpr int CCOL = TL*CH;          // 135 combined (t',o) columns
constexpr int ZLD = 136;             // padded Z row stride
constexpr int CONV_H = 88, CONV_W = 43, FEAT = CONV_H*CONV_W; // 3784
constexpr int FLATD = TL*FEAT;       // 11352
constexpr int HLD = 48;              // padded h row stride (b128-aligned)

// workspace layout (float offsets)
constexpr size_t OFF_CSUM = 0;
constexpr size_t OFF_LAM  = 256;
constexpr size_t OFF_BEFF = 1024;
constexpr size_t OFF_M    = 1056;
constexpr size_t OFF_MA   = 3104;
constexpr size_t OFF_WEFF = 5152;
constexpr size_t OFF_L    = 32768;                    // 768*8100
constexpr size_t OFF_Z    = 6291456;                  // 3*256*90*136
constexpr size_t OFF_X    = 15728640;                 // 256*11352

// ============================================================================
// k_corr: normalize rows -> yT (swizzled), pearson corr -> L (global),
// row sums via LDS atomics, uncertainty-head partial into csum.
// ============================================================================
__global__ __launch_bounds__(TPB) void k_corr(const float* __restrict__ fdata,
    const float* __restrict__ unw, const float* __restrict__ unb,
    float* __restrict__ Lout, float* __restrict__ csum)
{
    __shared__ float yT[65*96];      // 24,960 B
    __shared__ float Dl[NV], Wd[NV];
    __shared__ float red[TPB];

    const int q = blockIdx.x, tid = threadIdx.x;
    const int t = q >> 8, b = q & 255;
    const float* xp = fdata + ((size_t)b*TL + t)*NS;
    const int wave = tid >> 6, lane = tid & 63;

    if (tid < NV) Dl[tid] = 0.f;

    // ---- normalize + uncertainty partial ----
    float up = 0.f;
    for (int n = wave; n < NV; n += 4) {
        const float* row = xp + n*SV;
        float va = row[lane];
        float vb = (lane == 0) ? row[64] : 0.f;
        up += va*unw[n*SV + lane];
        if (lane == 0) up += vb*unw[n*SV + 64];
        float s1 = va + vb, s2 = va*va + vb*vb;
        #pragma unroll
        for (int o = 1; o < 64; o <<= 1) { s1 += __shfl_xor(s1, o); s2 += __shfl_xor(s2, o); }
        float mean = s1 / SV;
        float var  = s2 - SV*mean*mean;
        float inv  = 1.f / (sqrtf(fmaxf(var, 0.f)) + 1e-6f);
        yT[lane*96 + (((n >> 2) + lane) % 24)*4 + (n & 3)] = (va - mean)*inv;
        if (lane == 0)
            yT[64*96 + (((n >> 2) + 64) % 24)*4 + (n & 3)] = (vb - mean)*inv;
    }
    red[tid] = up; __syncthreads();
    if (tid < 128) red[tid] += red[tid+128]; __syncthreads();
    if (tid < 64)  red[tid] += red[tid+64];  __syncthreads();
    if (tid < 64) {
        float x = red[tid];
        #pragma unroll
        for (int o = 32; o >= 1; o >>= 1) x += __shfl_down(x, o);
        if (tid == 0) {
            float u = x + unb[0];
            atomicAdd(csum + (q/3), 1.f/(1.f + expf(-u)));
        }
    }
    __syncthreads();

    // ---- corr tiles -> W -> off-diag L stores + row-sum atomics ----
    float* Lq = Lout + (size_t)q*NM;
    for (int tile = tid; tile < 529; tile += TPB) {     // 23x23 tiles of 4x4
        int tr = tile / 23, tc = tile - tr*23;
        int n0 = 4*tr, m0 = 4*tc;
        int ca = tr, cb = tc;
        float acc[4][4] = {};
        for (int s = 0; s < SV; ++s) {
            const float* base = &yT[s*96];
            float4 a4 = *(const float4*)(base + 4*ca);
            float4 b4 = *(const float4*)(base + 4*cb);
            float av[4] = {a4.x, a4.y, a4.z, a4.w};
            float bv[4] = {b4.x, b4.y, b4.z, b4.w};
            #pragma unroll
            for (int i = 0; i < 4; ++i)
                #pragma unroll
                for (int j = 0; j < 4; ++j) acc[i][j] += av[i]*bv[j];
            if (++ca == 24) ca = 0;
            if (++cb == 24) cb = 0;
        }
        #pragma unroll
        for (int i = 0; i < 4; ++i) {
            int n = n0 + i;
            if (n >= NV) break;
            float rsum = 0.f;
            #pragma unroll
            for (int j = 0; j < 4; ++j) {
                int m = m0 + j;
                if (m < NV) {
                    float w = (acc[i][j] + 1.f)*0.5f;
                    rsum += w;
                    if (n != m) Lq[n*NV + m] = -w;
                    else        Wd[n] = w;
                }
            }
            atomicAdd(&Dl[n], rsum);
        }
    }
    __syncthreads();
    if (tid < NV) Lq[tid*(NV+1)] = Dl[tid] - Wd[tid];
}

// ============================================================================
// k_eig: one wave per q. Lane owns rows {lane, 64+lane} in registers; v shared
// via per-wave LDS (wave-synchronous: NO block barriers needed).
// ============================================================================
__global__ __launch_bounds__(TPB) void k_eig(const float* __restrict__ L,
                                             float* __restrict__ lamOut)
{
    __shared__ float vbuf[4][2][92];
    const int tid = threadIdx.x, w = tid >> 6, lane = tid & 63;
    const int q = blockIdx.x*4 + w;
    const float* Lq = L + (size_t)q*NM;

    float LA[92], LB[92];
    {
        const float2* ra = (const float2*)(Lq + lane*NV);
        #pragma unroll
        for (int j = 0; j < 45; ++j) { float2 x = ra[j]; LA[2*j] = x.x; LA[2*j+1] = x.y; }
        LA[90] = 0.f; LA[91] = 0.f;
        if (lane < 26) {
            const float2* rb = (const float2*)(Lq + (64 + lane)*NV);
            #pragma unroll
            for (int j = 0; j < 45; ++j) { float2 x = rb[j]; LB[2*j] = x.x; LB[2*j+1] = x.y; }
        } else {
            #pragma unroll
            for (int j = 0; j < 90; ++j) LB[j] = 0.f;
        }
        LB[90] = 0.f; LB[91] = 0.f;
    }
    if (lane < 2) { vbuf[w][0][90+lane] = 0.f; vbuf[w][1][90+lane] = 0.f; }
    __builtin_amdgcn_wave_barrier();

    float vA = sinf(1.3f*lane + 0.5f) + 0.05f;
    float vB = (lane < 26) ? (sinf(1.3f*(64 + lane) + 0.5f) + 0.05f) : 0.f;
    int cur = 0;
    float wA = 0.f, wB = 0.f;

    auto share = [&]() {
        vbuf[w][cur][lane] = vA;
        if (lane < 26) vbuf[w][cur][64 + lane] = vB;
        __builtin_amdgcn_wave_barrier();
    };
    auto matvec = [&](float sigma) {
        const float4* v4 = (const float4*)&vbuf[w][cur][0];
        float p0=0.f,p1=0.f,p2=0.f,p3=0.f, r0=0.f,r1=0.f,r2=0.f,r3=0.f;
        #pragma unroll
        for (int j = 0; j < 23; ++j) {
            float4 x = v4[j];
            p0 += LA[4*j]*x.x;   p1 += LA[4*j+1]*x.y;
            p2 += LA[4*j+2]*x.z; p3 += LA[4*j+3]*x.w;
            r0 += LB[4*j]*x.x;   r1 += LB[4*j+1]*x.y;
            r2 += LB[4*j+2]*x.z; r3 += LB[4*j+3]*x.w;
        }
        wA = (p0+p1) + (p2+p3) - sigma*vA;
        wB = (r0+r1) + (r2+r3) - sigma*vB;
        __builtin_amdgcn_wave_barrier();
        cur ^= 1;
    };
    auto renorm = [&]() {
        float t1 = vA + ((lane < 26) ? vB : 0.f);
        float t2 = vA*vA + ((lane < 26) ? vB*vB : 0.f);
        #pragma unroll
        for (int o = 1; o < 64; o <<= 1) { t1 += __shfl_xor(t1, o); t2 += __shfl_xor(t2, o); }
        float mean = t1*(1.f/90.f);
        float ns   = t2 - 90.f*mean*mean;
        float rn   = rsqrtf(fmaxf(ns, 1e-30f));
        vA = (vA - mean)*rn; vB = (vB - mean)*rn;
    };
    auto dotvw = [&]() {
        float d = vA*wA + ((lane < 26) ? vB*wB : 0.f);
        #pragma unroll
        for (int o = 1; o < 64; o <<= 1) d += __shfl_xor(d, o);
        return d;
    };

    for (int it = 0; it < 8; ++it) { share(); matvec(0.f); vA = wA; vB = wB; }
    renorm();
    share(); matvec(0.f);
    float ray = dotvw();
    float sigma = 0.45f*ray;
    vA = wA - sigma*vA; vB = wB - sigma*vB;
    for (int it = 0; it < 87; ++it) {
        if ((it & 7) == 7) renorm();
        share(); matvec(sigma); vA = wA; vB = wB;
    }
    renorm();
    share(); matvec(0.f);
    float lam = dotvw();
    if (lane == 0) lamOut[q] = lam;
}

// ============================================================================
// k_Z: Z[k][b][m][tp*45+o] = sum_s fdata[b,tp,m,s] * theta[k,s,o]
// ============================================================================
__global__ __launch_bounds__(TPB) void k_Z(const float* __restrict__ fdata,
                                           const float* __restrict__ theta,
                                           float* __restrict__ Z)
{
    __shared__ float fl[NV][69];
    __shared__ float thl[3][SV][48];

    const int g = blockIdx.x, tid = threadIdx.x;
    const int b = g/3, tp = g - 3*b;
    const float* fp = fdata + ((size_t)b*TL + tp)*NS;

    for (int idx = tid; idx < NS; idx += TPB) {
        int m = idx / SV, s = idx - m*SV;
        fl[m][s] = fp[idx];
    }
    for (int idx = tid; idx < 3*SV*48; idx += TPB) {
        int k = idx / (SV*48), rr = idx - k*(SV*48);
        int s = rr / 48, o = rr - s*48;
        thl[k][s][o] = (o < CH) ? theta[(k*SV + s)*CH + o] : 0.f;
    }
    __syncthreads();

    for (int tile = tid; tile < 414; tile += TPB) {
        int mt = tile / 18, ct = tile - mt*18;
        int k = ct / 6, ot = ct - 6*k;
        int m0 = 4*mt, o0 = 8*ot;
        float acc[4][8] = {};
        for (int s = 0; s < SV; ++s) {
            float a0 = fl[m0][s], a1 = fl[m0+1][s], a2 = fl[m0+2][s], a3 = fl[m0+3][s];
            float4 t0 = *(const float4*)&thl[k][s][o0];
            float4 t1 = *(const float4*)&thl[k][s][o0+4];
            float tv[8] = {t0.x,t0.y,t0.z,t0.w,t1.x,t1.y,t1.z,t1.w};
            #pragma unroll
            for (int j = 0; j < 8; ++j) {
                acc[0][j] += a0*tv[j]; acc[1][j] += a1*tv[j];
                acc[2][j] += a2*tv[j]; acc[3][j] += a3*tv[j];
            }
        }
        #pragma unroll
        for (int i = 0; i < 4; ++i) {
            int m = m0 + i; if (m >= NV) break;
            float* zp = Z + ((size_t)(k*BSZ + b)*NV + m)*ZLD + tp*CH;
            #pragma unroll
            for (int j = 0; j < 8; ++j) {
                int o = o0 + j;
                if (o < CH) zp[o] = acc[i][j];
            }
        }
    }
    if (tp == 2) {    // zero pad col 135
        for (int idx = tid; idx < 3*NV; idx += TPB) {
            int k = idx / NV, m = idx - k*NV;
            Z[((size_t)(k*BSZ + b)*NV + m)*ZLD + 135] = 0.f;
        }
    }
}

// ============================================================================
// k_hc (512 thr): h = relu(Z0 + Lt@Z1 + (2Lt^2)@Z2 - Z2) -> 3x3x3 conv -> relu
// -> 1x1 conv -> *csum -> X.  Weights in LDS, padded h rows, Z prefetch.
// LDS: 13,344 floats = 53,376 B -> 3 blocks/CU, 24 waves/CU.
// ============================================================================
__global__ __launch_bounds__(TPH) void k_hc(const float* __restrict__ L,
    const float* __restrict__ lam, const float* __restrict__ Z,
    const float* __restrict__ tw, const float* __restrict__ tb,
    const float* __restrict__ ow, const float* __restrict__ ob,
    const float* __restrict__ csum, float* __restrict__ X)
{
    __shared__ float smem[13344];        // A(8280) / h(3*90*48=12960) + wt(384)
    float* wtl = &smem[12960];
    const int q = blockIdx.x, tid = threadIdx.x;
    const int t = q >> 8, b = q & 255;
    const float il2 = 2.0f / lam[q];

    // stage A = Lt (stride 92) and conv weights
    for (int idx = tid; idx < NM; idx += TPH) {
        int i = idx / NV, j = idx - i*NV;
        smem[i*92 + j] = il2 * L[(size_t)q*NM + idx] - ((i == j) ? 1.f : 0.f);
    }
    if (tid < 270) {
        int f = tid / 27, r = tid - f*27;
        int w9 = r / 3, dj = r - 3*w9;
        wtl[(f*9 + w9)*4 + dj] = tw[tid];
    } else if (tid < 280) wtl[360 + (tid - 270)] = tb[tid - 270];
    else if (tid < 290)   wtl[370 + (tid - 280)] = ow[tid - 280];
    __syncthreads();

    // GEMM: 30 row-tiles (3 rows) x 17 col-tiles (8 cols) = 510 threads
    float acc[3][8];
    const int tn = tid / 17, tc = tid - tn*17;
    const int n0 = 3*tn, c0 = 8*tc;
    const bool act = (tid < 510);
    if (act) {
        #pragma unroll
        for (int i = 0; i < 3; ++i)
            #pragma unroll
            for (int j = 0; j < 8; ++j) acc[i][j] = 0.f;
        const float* z1p = Z + ((size_t)(BSZ + b)*NV)*ZLD + c0;
        const float* z2p = Z + ((size_t)(2*BSZ + b)*NV)*ZLD + c0;
        float4 nz1a = *(const float4*)(z1p),     nz1b = *(const float4*)(z1p + 4);
        float4 nz2a = *(const float4*)(z2p),     nz2b = *(const float4*)(z2p + 4);
        for (int m = 0; m < NV; ++m) {
            float4 z1a = nz1a, z1b = nz1b, z2a = nz2a, z2b = nz2b;
            if (m < NV-1) {
                const float* p1 = z1p + (size_t)(m+1)*ZLD;
                const float* p2 = z2p + (size_t)(m+1)*ZLD;
                nz1a = *(const float4*)(p1); nz1b = *(const float4*)(p1 + 4);
                nz2a = *(const float4*)(p2); nz2b = *(const float4*)(p2 + 4);
            }
            const float* ar = &smem[m*92 + n0];
            float av[3] = {ar[0], ar[1], ar[2]};
            float zv1[8] = {z1a.x,z1a.y,z1a.z,z1a.w,z1b.x,z1b.y,z1b.z,z1b.w};
            float zv2[8] = {z2a.x,z2a.y,z2a.z,z2a.w,z2b.x,z2b.y,z2b.z,z2b.w};
            #pragma unroll
            for (int i = 0; i < 3; ++i) {
                float a = av[i], bb = 2.f*a*a;
                #pragma unroll
                for (int j = 0; j < 8; ++j) acc[i][j] += a*zv1[j] + bb*zv2[j];
            }
        }
    }
    __syncthreads();                      // A region dead

    // epilogue: + Z0 - Z2, relu, write padded h tile (overlays A)
    float (*hl)[NV][HLD] = (float (*)[NV][HLD])smem;
    if (act) {
        const float* z0p = Z + ((size_t)b*NV)*ZLD;
        const float* z2p = Z + ((size_t)(2*BSZ + b)*NV)*ZLD;
        #pragma unroll
        for (int i = 0; i < 3; ++i) {
            int n = n0 + i;
            const float4* z0r = (const float4*)(z0p + (size_t)n*ZLD + c0);
            const float4* z2r = (const float4*)(z2p + (size_t)n*ZLD + c0);
            float4 z0a = z0r[0], z0b = z0r[1];
            float4 w2a = z2r[0], w2b = z2r[1];
            float zv0[8] = {z0a.x,z0a.y,z0a.z,z0a.w,z0b.x,z0b.y,z0b.z,z0b.w};
            float zv2[8] = {w2a.x,w2a.y,w2a.z,w2a.w,w2b.x,w2b.y,w2b.z,w2b.w};
            #pragma unroll
            for (int j = 0; j < 8; ++j) {
                int c = c0 + j;
                if (c < CCOL) {
                    float v = fmaxf(acc[i][j] + zv0[j] - zv2[j], 0.f);
                    hl[c/CH][n][c - (c/CH)*CH] = v;
                }
            }
        }
    }
    __syncthreads();

    // conv: 88 rows x 6 groups of 8 px = 528 threads, window in registers
    if (tid < 528) {
        const float cs  = csum[b];
        const float obv = ob[0];
        float* Xo = X + (size_t)b*FLATD + (size_t)t*FEAT;
        const int i = tid / 6, jg = tid - (tid/6)*6, j0 = 8*jg;
        float win[9][12];
        #pragma unroll
        for (int tp = 0; tp < 3; ++tp)
            #pragma unroll
            for (int di = 0; di < 3; ++di) {
                const float4* hr = (const float4*)&hl[tp][i + di][j0];
                float4 ha = hr[0], hb = hr[1], hc4 = hr[2];
                float* wr = win[tp*3 + di];
                wr[0]=ha.x; wr[1]=ha.y; wr[2]=ha.z; wr[3]=ha.w;
                wr[4]=hb.x; wr[5]=hb.y; wr[6]=hb.z; wr[7]=hb.w;
                wr[8]=hc4.x; wr[9]=hc4.y; wr[10]=hc4.z; wr[11]=hc4.w;
            }
        float opix[8] = {};
        #pragma unroll
        for (int f = 0; f < 10; ++f) {
            float c[8];
            float bv = wtl[360 + f];
            #pragma unroll
            for (int px = 0; px < 8; ++px) c[px] = bv;
            #pragma unroll
            for (int w9 = 0; w9 < 9; ++w9) {
                float4 t4 = *(const float4*)&wtl[(f*9 + w9)*4];
                const float* wr = win[w9];
                #pragma unroll
                for (int px = 0; px < 8; ++px)
                    c[px] += wr[px]*t4.x + wr[px+1]*t4.y + wr[px+2]*t4.z;
            }
            float o = wtl[370 + f];
            #pragma unroll
            for (int px = 0; px < 8; ++px) opix[px] += fmaxf(c[px], 0.f)*o;
        }
        #pragma unroll
        for (int px = 0; px < 8; ++px) {
            int j = j0 + px;
            if (j < CONV_W) Xo[i*CONV_W + j] = (opix[px] + obv)*cs;
        }
    }
}

// ---------------- FC collapse ----------------
__global__ void k_eff1(const float* __restrict__ W2, const float* __restrict__ g2,
                       const float* __restrict__ W3, const float* __restrict__ g1,
                       float* __restrict__ M, float* __restrict__ Ma)
{
    int gid = blockIdx.x*TPB + threadIdx.x;
    if (gid >= 2048) return;
    int i = gid >> 1, c = gid & 1;
    const float rs = rsqrtf(1.f + 1e-5f);
    float acc = 0.f;
    for (int j = 0; j < 256; ++j) acc += W2[i*256 + j]*(g2[j]*rs)*W3[j*2 + c];
    M[gid]  = acc;
    Ma[gid] = acc*(g1[i]*rs);
}

__global__ void k_effb(const float* __restrict__ M, const float* __restrict__ W3,
                       const float* __restrict__ b1, const float* __restrict__ bb1, const float* __restrict__ g1,
                       const float* __restrict__ b2, const float* __restrict__ bb2, const float* __restrict__ g2,
                       const float* __restrict__ b3, float* __restrict__ beff)
{
    __shared__ float r0[TPB], r1[TPB];
    int tid = threadIdx.x;
    const float rs = rsqrtf(1.f + 1e-5f);
    float a0 = 0.f, a1 = 0.f;
    for (int i = tid; i < 1024; i += TPB) {
        float wv = b1[i]*(g1[i]*rs) + bb1[i];
        a0 += wv*M[2*i]; a1 += wv*M[2*i+1];
    }
    for (int j = tid; j < 256; j += TPB) {
        float wv = b2[j]*(g2[j]*rs) + bb2[j];
        a0 += wv*W3[2*j]; a1 += wv*W3[2*j+1];
    }
    r0[tid] = a0; r1[tid] = a1; __syncthreads();
    if (tid < 128) { r0[tid] += r0[tid+128]; r1[tid] += r1[tid+128]; } __syncthreads();
    if (tid < 64)  { r0[tid] += r0[tid+64];  r1[tid] += r1[tid+64];  } __syncthreads();
    if (tid < 64) {
        float x0 = r0[tid], x1 = r1[tid];
        #pragma unroll
        for (int o = 32; o >= 1; o >>= 1) { x0 += __shfl_down(x0, o); x1 += __shfl_down(x1, o); }
        if (tid == 0) { beff[0] = x0 + b3[0]; beff[1] = x1 + b3[1]; }
    }
}

__global__ void k_eff2(const float* __restrict__ W1, const float* __restrict__ Ma,
                       float* __restrict__ Weff)
{
    int tid = threadIdx.x;
    int r = blockIdx.x*4 + (tid >> 6);
    int lane = tid & 63;
    if (r >= FLATD) return;
    const float* wrow = W1 + (size_t)r*1024;
    float a0 = 0.f, a1 = 0.f;
    for (int i = lane; i < 1024; i += 64) {
        float w = wrow[i];
        a0 += w*Ma[2*i]; a1 += w*Ma[2*i+1];
    }
    #pragma unroll
    for (int o = 32; o >= 1; o >>= 1) { a0 += __shfl_down(a0, o); a1 += __shfl_down(a1, o); }
    if (lane == 0) { Weff[2*r] = a0; Weff[2*r+1] = a1; }
}

__global__ void k_logits(const float* __restrict__ x, const float* __restrict__ Weff,
                         const float* __restrict__ beff, float* __restrict__ out)
{
    __shared__ float r0[TPB], r1[TPB];
    int b = blockIdx.x, tid = threadIdx.x;
    const float* xr = x + (size_t)b*FLATD;
    float a0 = 0.f, a1 = 0.f;
    for (int i = tid; i < FLATD; i += TPB) {
        float v = xr[i];
        a0 += v*Weff[2*i]; a1 += v*Weff[2*i+1];
    }
    r0[tid] = a0; r1[tid] = a1; __syncthreads();
    if (tid < 128) { r0[tid] += r0[tid+128]; r1[tid] += r1[tid+128]; } __syncthreads();
    if (tid < 64)  { r0[tid] += r0[tid+64];  r1[tid] += r1[tid+64];  } __syncthreads();
    if (tid < 64) {
        float x0 = r0[tid], x1 = r1[tid];
        #pragma unroll
        for (int o = 32; o >= 1; o >>= 1) { x0 += __shfl_down(x0, o); x1 += __shfl_down(x1, o); }
        if (tid == 0) {
            float l0 = x0 + beff[0], l1 = x1 + beff[1];
            float mx = fmaxf(l0, l1);
            float e0 = expf(l0 - mx), e1 = expf(l1 - mx);
            float s = e0 + e1;
            out[2*b]     = e0/s;
            out[2*b + 1] = e1/s;
        }
    }
}

extern "C" void kernel_launch(void* const* d_in, const int* in_sizes, int n_in,
                              void* d_out, int out_size, void* d_ws, size_t ws_size,
                              hipStream_t stream)
{
    const float* fdata = (const float*)d_in[0];
    const float* un_w  = (const float*)d_in[1];
    const float* un_b  = (const float*)d_in[2];
    const float* theta = (const float*)d_in[3];
    const float* tcw   = (const float*)d_in[4];
    const float* tcb   = (const float*)d_in[5];
    const float* ocw   = (const float*)d_in[6];
    const float* ocb   = (const float*)d_in[7];
    const float* l1w   = (const float*)d_in[8];
    const float* l1b   = (const float*)d_in[9];
    const float* bn1g  = (const float*)d_in[10];
    const float* bn1b  = (const float*)d_in[11];
    const float* l2w   = (const float*)d_in[12];
    const float* l2b   = (const float*)d_in[13];
    const float* bn2g  = (const float*)d_in[14];
    const float* bn2b  = (const float*)d_in[15];
    const float* l3w   = (const float*)d_in[16];
    const float* l3b   = (const float*)d_in[17];

    float* ws   = (float*)d_ws;
    float* csum = ws + OFF_CSUM;
    float* lam  = ws + OFF_LAM;
    float* beff = ws + OFF_BEFF;
    float* M    = ws + OFF_M;
    float* Ma   = ws + OFF_MA;
    float* Weff = ws + OFF_WEFF;
    float* L    = ws + OFF_L;
    float* Z    = ws + OFF_Z;
    float* X    = ws + OFF_X;
    float* out  = (float*)d_out;

    hipMemsetAsync(csum, 0, BSZ*sizeof(float), stream);
    k_corr <<<NP, TPB, 0, stream>>>(fdata, un_w, un_b, L, csum);
    k_eig  <<<NP/4, TPB, 0, stream>>>(L, lam);
    k_Z    <<<BSZ*TL, TPB, 0, stream>>>(fdata, theta, Z);
    k_hc   <<<NP, TPH, 0, stream>>>(L, lam, Z, tcw, tcb, ocw, ocb, csum, X);
    k_eff1 <<<8, TPB, 0, stream>>>(l2w, bn2g, l3w, bn1g, M, Ma);
    k_effb <<<1, TPB, 0, stream>>>(M, l3w, l1b, bn1b, bn1g, l2b, bn2b, bn2g, l3b, beff);
    k_eff2 <<<(FLATD + 3)/4, TPB, 0, stream>>>(l1w, Ma, Weff);
    k_logits<<<BSZ, TPB, 0, stream>>>(X, Weff, beff, out);
}